// Round 1
// baseline (638.066 us; speedup 1.0000x reference)
//
#include <hip/hip_runtime.h>
#include <math.h>

#define BB 16
#define NL 4096
#define NH 1024
#define CL 128
#define CHH 256
#define KIN 384     // CL + CHH
#define CO 256      // output channels both layers
#define BN_EPS 1e-5f

// ---------------------------------------------------------------------------
// 1. transpose feat_high (B, CH, NH) -> fT (B, NH, CH)
// ---------------------------------------------------------------------------
__global__ __launch_bounds__(256) void k_transpose_fh(const float* __restrict__ fh,
                                                      float* __restrict__ fT) {
    __shared__ float s[32][33];
    int b = blockIdx.z;
    int c0 = blockIdx.y * 32;
    int m0 = blockIdx.x * 32;
    int tx = threadIdx.x % 32, ty = threadIdx.x / 32;   // 32 x 8
    const float* src = fh + (size_t)b * CHH * NH;
    float* dst = fT + (size_t)b * NH * CHH;
#pragma unroll
    for (int j = 0; j < 4; j++)
        s[ty + 8 * j][tx] = src[(size_t)(c0 + ty + 8 * j) * NH + m0 + tx];
    __syncthreads();
#pragma unroll
    for (int j = 0; j < 4; j++)
        dst[(size_t)(m0 + ty + 8 * j) * CHH + c0 + tx] = s[tx][ty + 8 * j];
}

// ---------------------------------------------------------------------------
// 2. 3-NN search. Replicates reference arithmetic order bit-faithfully:
//    d2 = (sum(xl^2) + sum(xh^2)) - 2*dot   with sequential IEEE f32 ops,
//    compare on d = sqrtf(max(d2,0)), strict < keeps lower index on ties
//    (matches stable descending top_k on -d).
// ---------------------------------------------------------------------------
__global__ __launch_bounds__(256) void k_knn(const float* __restrict__ xyzl,
                                             const float* __restrict__ xyzh,
                                             int* __restrict__ idx,
                                             float* __restrict__ wgt) {
    __shared__ float xh0[NH], xh1[NH], xh2[NH], bh[NH];
    int b = blockIdx.y;
    int n = blockIdx.x * 256 + threadIdx.x;
    const float* xh = xyzh + (size_t)b * NH * 3;
    for (int e = threadIdx.x; e < NH * 3; e += 256) {
        float v = xh[e];
        int p = e / 3, dax = e - 3 * p;
        if (dax == 0) xh0[p] = v;
        else if (dax == 1) xh1[p] = v;
        else xh2[p] = v;
    }
    __syncthreads();
    for (int p = threadIdx.x; p < NH; p += 256) {
        float x0 = xh0[p], x1 = xh1[p], x2 = xh2[p];
        bh[p] = __fadd_rn(__fadd_rn(__fmul_rn(x0, x0), __fmul_rn(x1, x1)),
                          __fmul_rn(x2, x2));
    }
    __syncthreads();

    const float* xl = xyzl + ((size_t)b * NL + n) * 3;
    float l0 = xl[0], l1 = xl[1], l2 = xl[2];
    float a = __fadd_rn(__fadd_rn(__fmul_rn(l0, l0), __fmul_rn(l1, l1)),
                        __fmul_rn(l2, l2));

    float d0 = INFINITY, d1 = INFINITY, d2v = INFINITY;
    int i0 = 0, i1 = 0, i2 = 0;
    for (int m = 0; m < NH; m++) {
        float t = __fadd_rn(__fadd_rn(__fmul_rn(l0, xh0[m]), __fmul_rn(l1, xh1[m])),
                            __fmul_rn(l2, xh2[m]));
        float dd = __fsub_rn(__fadd_rn(a, bh[m]), __fmul_rn(2.0f, t));
        float d = sqrtf(fmaxf(dd, 0.0f));
        if (d < d2v) {
            if (d < d0)      { d2v = d1; i2 = i1; d1 = d0; i1 = i0; d0 = d; i0 = m; }
            else if (d < d1) { d2v = d1; i2 = i1; d1 = d;  i1 = m; }
            else             { d2v = d;  i2 = m; }
        }
    }
    float w0 = 1.0f / fmaxf(d0, 1e-8f);
    float w1 = 1.0f / fmaxf(d1, 1e-8f);
    float w2 = 1.0f / fmaxf(d2v, 1e-8f);
    float wsum = __fadd_rn(__fadd_rn(w0, w1), w2);
    w0 /= wsum; w1 /= wsum; w2 /= wsum;

    size_t base = ((size_t)b * NL + n) * 3;
    idx[base] = i0; idx[base + 1] = i1; idx[base + 2] = i2;
    wgt[base] = w0; wgt[base + 1] = w1; wgt[base + 2] = w2;
}

// ---------------------------------------------------------------------------
// 3. interpolate: xi[b][c][n] = sum_k w[k] * fT[b][idx[k]][c]   (c in [0,256))
// ---------------------------------------------------------------------------
__global__ __launch_bounds__(256) void k_interp(const float* __restrict__ fT,
                                                const int* __restrict__ idx,
                                                const float* __restrict__ wgt,
                                                float* __restrict__ xi) {
    __shared__ float T[16][CHH + 1];
    int b = blockIdx.y;
    int n0 = blockIdx.x * 16;
    int c = threadIdx.x;
    const float* fTb = fT + (size_t)b * NH * CHH;
    for (int j = 0; j < 16; j++) {
        size_t base = ((size_t)b * NL + n0 + j) * 3;
        int m0 = idx[base], m1 = idx[base + 1], m2 = idx[base + 2];
        float w0 = wgt[base], w1 = wgt[base + 1], w2 = wgt[base + 2];
        float f0 = fTb[(size_t)m0 * CHH + c];
        float f1 = fTb[(size_t)m1 * CHH + c];
        float f2 = fTb[(size_t)m2 * CHH + c];
        T[j][c] = __fadd_rn(__fadd_rn(__fmul_rn(w0, f0), __fmul_rn(w1, f1)),
                            __fmul_rn(w2, f2));
    }
    __syncthreads();
    int jj = threadIdx.x % 16;
    int r0 = threadIdx.x / 16;
    float* xib = xi + (size_t)b * CHH * NL;
#pragma unroll
    for (int ch = 0; ch < 16; ch++) {
        int cc = ch * 16 + r0;
        xib[(size_t)cc * NL + n0 + jj] = T[jj][cc];
    }
}

// ---------------------------------------------------------------------------
// 4. f32 GEMM: out[b][o][n] = sum_c W[o][c] * X[b][c][n] + bias[o]
//    LAYER 0: X rows [0,256) from xi, [256,384) from feat_low.
//    LAYER 1: X = relu(scale[c]*y0 + shift[c])  (fused BN+ReLU on load)
//    64x128 tile, BK=16, 256 threads, 4x8 micro-tile.
// ---------------------------------------------------------------------------
template <int LAYER>
__global__ __launch_bounds__(256) void k_gemm(const float* __restrict__ Bsrc0,
                                              const float* __restrict__ Bsrc1,
                                              const float* __restrict__ W,
                                              const float* __restrict__ bias,
                                              const float* __restrict__ scale,
                                              const float* __restrict__ shift,
                                              float* __restrict__ out, int K) {
    const int BM = 64, BNt = 128, BK = 16;
    __shared__ float As[BK][BM];
    __shared__ float Bs[BK][BNt];
    int b = blockIdx.z;
    int m0 = blockIdx.y * BM;
    int n0 = blockIdx.x * BNt;
    int tid = threadIdx.x;
    int tn = tid % 16, tm = tid / 16;
    int am = tid / 4;
    int ak = (tid % 4) * 4;
    int bk = tid / 16;
    int bcol = (tid % 16) * 8;

    float acc[4][8] = {};

    for (int k0 = 0; k0 < K; k0 += BK) {
        float4 av = *(const float4*)&W[(size_t)(m0 + am) * K + k0 + ak];
        As[ak][am] = av.x; As[ak + 1][am] = av.y;
        As[ak + 2][am] = av.z; As[ak + 3][am] = av.w;

        int cg = k0 + bk;
        const float* src;
        if (LAYER == 0) {
            src = (cg < CHH) ? (Bsrc0 + ((size_t)b * CHH + cg) * NL)
                             : (Bsrc1 + ((size_t)b * CL + (cg - CHH)) * NL);
        } else {
            src = Bsrc0 + ((size_t)b * CO + cg) * NL;
        }
        float4 v0 = *(const float4*)&src[n0 + bcol];
        float4 v1 = *(const float4*)&src[n0 + bcol + 4];
        if (LAYER == 1) {
            float sc = scale[cg], sh = shift[cg];
            v0.x = fmaxf(fmaf(sc, v0.x, sh), 0.f);
            v0.y = fmaxf(fmaf(sc, v0.y, sh), 0.f);
            v0.z = fmaxf(fmaf(sc, v0.z, sh), 0.f);
            v0.w = fmaxf(fmaf(sc, v0.w, sh), 0.f);
            v1.x = fmaxf(fmaf(sc, v1.x, sh), 0.f);
            v1.y = fmaxf(fmaf(sc, v1.y, sh), 0.f);
            v1.z = fmaxf(fmaf(sc, v1.z, sh), 0.f);
            v1.w = fmaxf(fmaf(sc, v1.w, sh), 0.f);
        }
        *(float4*)&Bs[bk][bcol] = v0;
        *(float4*)&Bs[bk][bcol + 4] = v1;
        __syncthreads();

#pragma unroll
        for (int kk = 0; kk < BK; kk++) {
            float4 aa = *(const float4*)&As[kk][tm * 4];
            float4 b0 = *(const float4*)&Bs[kk][tn * 8];
            float4 b1 = *(const float4*)&Bs[kk][tn * 8 + 4];
            float av4[4] = {aa.x, aa.y, aa.z, aa.w};
            float bv[8] = {b0.x, b0.y, b0.z, b0.w, b1.x, b1.y, b1.z, b1.w};
#pragma unroll
            for (int i = 0; i < 4; i++)
#pragma unroll
                for (int j = 0; j < 8; j++)
                    acc[i][j] = fmaf(av4[i], bv[j], acc[i][j]);
        }
        __syncthreads();
    }

#pragma unroll
    for (int i = 0; i < 4; i++) {
        int mo = m0 + tm * 4 + i;
        float bi = bias[mo];
        float* orow = out + ((size_t)b * CO + mo) * NL + n0 + tn * 8;
        float4 s0 = make_float4(acc[i][0] + bi, acc[i][1] + bi,
                                acc[i][2] + bi, acc[i][3] + bi);
        float4 s1 = make_float4(acc[i][4] + bi, acc[i][5] + bi,
                                acc[i][6] + bi, acc[i][7] + bi);
        *(float4*)&orow[0] = s0;
        *(float4*)&orow[4] = s1;
    }
}

// ---------------------------------------------------------------------------
// 5. per-channel batch stats -> scale/shift  (block = one channel)
// ---------------------------------------------------------------------------
__global__ __launch_bounds__(256) void k_stats(const float* __restrict__ y,
                                               const float* __restrict__ gamma,
                                               const float* __restrict__ beta,
                                               float* __restrict__ scale,
                                               float* __restrict__ shift) {
    int o = blockIdx.x;
    double s = 0.0, sq = 0.0;
    for (int b = 0; b < BB; b++) {
        const float* row = y + ((size_t)b * CO + o) * NL;
        for (int i = threadIdx.x; i < NL; i += 256) {
            double v = (double)row[i];
            s += v; sq += v * v;
        }
    }
    __shared__ double ls[256], lq[256];
    ls[threadIdx.x] = s; lq[threadIdx.x] = sq;
    __syncthreads();
    for (int st = 128; st > 0; st >>= 1) {
        if (threadIdx.x < st) {
            ls[threadIdx.x] += ls[threadIdx.x + st];
            lq[threadIdx.x] += lq[threadIdx.x + st];
        }
        __syncthreads();
    }
    if (threadIdx.x == 0) {
        double N = (double)BB * NL;
        double mean = ls[0] / N;
        double var = lq[0] / N - mean * mean;
        float sc = gamma[o] / sqrtf((float)var + BN_EPS);
        scale[o] = sc;
        shift[o] = beta[o] - (float)mean * sc;
    }
}

// ---------------------------------------------------------------------------
// 6. final in-place BN + ReLU on d_out
// ---------------------------------------------------------------------------
__global__ __launch_bounds__(256) void k_bnrelu(float* __restrict__ y,
                                                const float* __restrict__ scale,
                                                const float* __restrict__ shift) {
    size_t i = (size_t)blockIdx.x * 256 + threadIdx.x;   // float4 index
    float4 v = ((float4*)y)[i];
    size_t e0 = i * 4;
    int c = (int)((e0 / NL) % CO);
    float sc = scale[c], sh = shift[c];
    v.x = fmaxf(fmaf(sc, v.x, sh), 0.f);
    v.y = fmaxf(fmaf(sc, v.y, sh), 0.f);
    v.z = fmaxf(fmaf(sc, v.z, sh), 0.f);
    v.w = fmaxf(fmaf(sc, v.w, sh), 0.f);
    ((float4*)y)[i] = v;
}

// ---------------------------------------------------------------------------
extern "C" void kernel_launch(void* const* d_in, const int* in_sizes, int n_in,
                              void* d_out, int out_size, void* d_ws, size_t ws_size,
                              hipStream_t stream) {
    const float* xyz_low   = (const float*)d_in[0];
    const float* xyz_high  = (const float*)d_in[1];
    const float* feat_low  = (const float*)d_in[2];
    const float* feat_high = (const float*)d_in[3];
    const float* W0  = (const float*)d_in[4];
    const float* b0  = (const float*)d_in[5];
    const float* g0  = (const float*)d_in[6];
    const float* be0 = (const float*)d_in[7];
    const float* W1  = (const float*)d_in[8];
    const float* b1  = (const float*)d_in[9];
    const float* g1  = (const float*)d_in[10];
    const float* be1 = (const float*)d_in[11];
    float* out = (float*)d_out;

    char* ws = (char*)d_ws;
    // layout: [y0: 64MB (first 16MB doubles as fT, dead before y0 written)]
    //         [xi: 64MB] [idx: 768KB] [wgt: 768KB] [params: 4KB]
    float* y0  = (float*)ws;
    float* fT  = (float*)ws;
    float* xi  = (float*)(ws + ((size_t)64 << 20));
    int*   idx = (int*)  (ws + ((size_t)128 << 20));
    float* wgt = (float*)(ws + ((size_t)128 << 20) + 786432);
    float* prm = (float*)(ws + ((size_t)128 << 20) + 2 * 786432);
    float* scale0 = prm, *shift0 = prm + 256, *scale1 = prm + 512, *shift1 = prm + 768;

    // 1. transpose feat_high
    k_transpose_fh<<<dim3(NH / 32, CHH / 32, BB), 256, 0, stream>>>(feat_high, fT);
    // 2. kNN
    k_knn<<<dim3(NL / 256, BB), 256, 0, stream>>>(xyz_low, xyz_high, idx, wgt);
    // 3. interpolate
    k_interp<<<dim3(NL / 16, BB), 256, 0, stream>>>(fT, idx, wgt, xi);
    // 4. layer 0 GEMM (+bias) -> y0
    k_gemm<0><<<dim3(NL / 128, CO / 64, BB), 256, 0, stream>>>(
        xi, feat_low, W0, b0, nullptr, nullptr, y0, KIN);
    // 5. stats for BN0
    k_stats<<<CO, 256, 0, stream>>>(y0, g0, be0, scale0, shift0);
    // 6. layer 1 GEMM with fused BN0+ReLU on load -> d_out (pre-BN1)
    k_gemm<1><<<dim3(NL / 128, CO / 64, BB), 256, 0, stream>>>(
        y0, nullptr, W1, b1, scale0, shift0, out, CO);
    // 7. stats for BN1
    k_stats<<<CO, 256, 0, stream>>>(out, g1, be1, scale1, shift1);
    // 8. final BN1 + ReLU in-place
    k_bnrelu<<<(BB * CO * NL / 4) / 256, 256, 0, stream>>>(out, scale1, shift1);
}

// Round 2
// 323.847 us; speedup vs baseline: 1.9703x; 1.9703x over previous
//
#include <hip/hip_runtime.h>
#include <math.h>

#define BB 16
#define NL 4096
#define NH 1024
#define CL 128
#define CHH 256
#define K0 384
#define K1 256
#define CO 256
#define BN_EPS 1e-5f

typedef __attribute__((ext_vector_type(8))) short bfrag;     // 8 bf16
typedef __attribute__((ext_vector_type(4))) float f32x4;
typedef __attribute__((ext_vector_type(4))) unsigned short ushort4b;

__device__ inline unsigned short f2bf(float f) {
    unsigned int u = __builtin_bit_cast(unsigned int, f);
    u += 0x7fffu + ((u >> 16) & 1u);                 // RNE
    return (unsigned short)(u >> 16);
}
__device__ inline float bf2f(unsigned short h) {
    unsigned int u = ((unsigned int)h) << 16;
    return __builtin_bit_cast(float, u);
}

// ---------------------------------------------------------------------------
// transpose feat_high (B, CH, NH) -> fT (B, NH, CH)   (f32, for the gather)
// ---------------------------------------------------------------------------
__global__ __launch_bounds__(256) void k_transpose_fh(const float* __restrict__ fh,
                                                      float* __restrict__ fT) {
    __shared__ float s[32][33];
    int b = blockIdx.z;
    int c0 = blockIdx.y * 32;
    int m0 = blockIdx.x * 32;
    int tx = threadIdx.x % 32, ty = threadIdx.x / 32;
    const float* src = fh + (size_t)b * CHH * NH;
    float* dst = fT + (size_t)b * NH * CHH;
#pragma unroll
    for (int j = 0; j < 4; j++)
        s[ty + 8 * j][tx] = src[(size_t)(c0 + ty + 8 * j) * NH + m0 + tx];
    __syncthreads();
#pragma unroll
    for (int j = 0; j < 4; j++)
        dst[(size_t)(m0 + ty + 8 * j) * CHH + c0 + tx] = s[tx][ty + 8 * j];
}

// ---------------------------------------------------------------------------
// 3-NN search — bit-faithful to reference (unchanged from round 1, passed)
// ---------------------------------------------------------------------------
__global__ __launch_bounds__(256) void k_knn(const float* __restrict__ xyzl,
                                             const float* __restrict__ xyzh,
                                             int* __restrict__ idx,
                                             float* __restrict__ wgt) {
    __shared__ float xh0[NH], xh1[NH], xh2[NH], bh[NH];
    int b = blockIdx.y;
    int n = blockIdx.x * 256 + threadIdx.x;
    const float* xh = xyzh + (size_t)b * NH * 3;
    for (int e = threadIdx.x; e < NH * 3; e += 256) {
        float v = xh[e];
        int p = e / 3, dax = e - 3 * p;
        if (dax == 0) xh0[p] = v;
        else if (dax == 1) xh1[p] = v;
        else xh2[p] = v;
    }
    __syncthreads();
    for (int p = threadIdx.x; p < NH; p += 256) {
        float x0 = xh0[p], x1 = xh1[p], x2 = xh2[p];
        bh[p] = __fadd_rn(__fadd_rn(__fmul_rn(x0, x0), __fmul_rn(x1, x1)),
                          __fmul_rn(x2, x2));
    }
    __syncthreads();

    const float* xl = xyzl + ((size_t)b * NL + n) * 3;
    float l0 = xl[0], l1 = xl[1], l2 = xl[2];
    float a = __fadd_rn(__fadd_rn(__fmul_rn(l0, l0), __fmul_rn(l1, l1)),
                        __fmul_rn(l2, l2));

    float d0 = INFINITY, d1 = INFINITY, d2v = INFINITY;
    int i0 = 0, i1 = 0, i2 = 0;
    for (int m = 0; m < NH; m++) {
        float t = __fadd_rn(__fadd_rn(__fmul_rn(l0, xh0[m]), __fmul_rn(l1, xh1[m])),
                            __fmul_rn(l2, xh2[m]));
        float dd = __fsub_rn(__fadd_rn(a, bh[m]), __fmul_rn(2.0f, t));
        float d = sqrtf(fmaxf(dd, 0.0f));
        if (d < d2v) {
            if (d < d0)      { d2v = d1; i2 = i1; d1 = d0; i1 = i0; d0 = d; i0 = m; }
            else if (d < d1) { d2v = d1; i2 = i1; d1 = d;  i1 = m; }
            else             { d2v = d;  i2 = m; }
        }
    }
    float w0 = 1.0f / fmaxf(d0, 1e-8f);
    float w1 = 1.0f / fmaxf(d1, 1e-8f);
    float w2 = 1.0f / fmaxf(d2v, 1e-8f);
    float wsum = __fadd_rn(__fadd_rn(w0, w1), w2);
    w0 /= wsum; w1 /= wsum; w2 /= wsum;

    size_t base = ((size_t)b * NL + n) * 3;
    idx[base] = i0; idx[base + 1] = i1; idx[base + 2] = i2;
    wgt[base] = w0; wgt[base + 1] = w1; wgt[base + 2] = w2;
}

// ---------------------------------------------------------------------------
// interpolate -> Xb[b][n][c] bf16, c in [0, 256)
// ---------------------------------------------------------------------------
__global__ __launch_bounds__(256) void k_interp(const float* __restrict__ fT,
                                                const int* __restrict__ idx,
                                                const float* __restrict__ wgt,
                                                unsigned short* __restrict__ Xb) {
    int b = blockIdx.y;
    int n0 = blockIdx.x * 16;
    int c = threadIdx.x;
    const float* fTb = fT + (size_t)b * NH * CHH;
    for (int j = 0; j < 16; j++) {
        size_t base = ((size_t)b * NL + n0 + j) * 3;
        int m0 = idx[base], m1 = idx[base + 1], m2 = idx[base + 2];
        float w0 = wgt[base], w1 = wgt[base + 1], w2 = wgt[base + 2];
        float f = __fadd_rn(__fadd_rn(__fmul_rn(w0, fTb[(size_t)m0 * CHH + c]),
                                      __fmul_rn(w1, fTb[(size_t)m1 * CHH + c])),
                            __fmul_rn(w2, fTb[(size_t)m2 * CHH + c]));
        Xb[((size_t)b * NL + n0 + j) * K0 + c] = f2bf(f);
    }
}

// ---------------------------------------------------------------------------
// feat_low (B, CL, NL) f32 -> Xb[b][n][256 + c] bf16   (transpose-convert)
// ---------------------------------------------------------------------------
__global__ __launch_bounds__(256) void k_fl_t(const float* __restrict__ fl,
                                              unsigned short* __restrict__ Xb) {
    __shared__ unsigned short s[32][68];
    int b = blockIdx.z, c0 = blockIdx.y * 32, n0 = blockIdx.x * 64;
    int tx = threadIdx.x & 63, ty = threadIdx.x >> 6;       // 64 x 4
    const float* src = fl + ((size_t)b * CL + c0) * NL + n0;
#pragma unroll
    for (int i = 0; i < 8; i++) {
        int c = ty * 8 + i;
        s[c][tx] = f2bf(src[(size_t)c * NL + tx]);
    }
    __syncthreads();
    int n = threadIdx.x >> 2, q = threadIdx.x & 3;
    ushort4b o0, o1;
#pragma unroll
    for (int e = 0; e < 4; e++) o0[e] = s[q * 8 + e][n];
#pragma unroll
    for (int e = 0; e < 4; e++) o1[e] = s[q * 8 + 4 + e][n];
    unsigned short* dst = Xb + ((size_t)b * NL + n0 + n) * K0 + CHH + c0 + q * 8;
    *(ushort4b*)dst = o0;
    *(ushort4b*)(dst + 4) = o1;
}

// ---------------------------------------------------------------------------
// f32 -> bf16 convert (weights)
// ---------------------------------------------------------------------------
__global__ __launch_bounds__(256) void k_cvt(const float* __restrict__ src,
                                             unsigned short* __restrict__ dst, int n) {
    int i = blockIdx.x * 256 + threadIdx.x;
    if (i < n) dst[i] = f2bf(src[i]);
}

// ---------------------------------------------------------------------------
// MFMA GEMM: C[m][n] = sum_k W[m][k] * X[n][k],  X n-major bf16.
// 128x128 tile, BK=32, 4 waves (64x64 each), XOR-swizzled LDS, double buffer.
// LAYER 0: out = y0[b][n][m] bf16 (+bias).  LAYER 1: out = f32 [b][m][n] (+bias).
// ---------------------------------------------------------------------------
__device__ inline int swz(int r, int cb) {
    return r * 32 + ((cb ^ ((r >> 1) & 3)) << 3);   // short index, 16B blocks
}

template <int LAYER>
__global__ __launch_bounds__(256) void k_gemm(const unsigned short* __restrict__ X,
                                              const unsigned short* __restrict__ Wb,
                                              const float* __restrict__ bias,
                                              void* __restrict__ outp) {
    const int K = (LAYER == 0) ? K0 : K1;
    __shared__ __align__(16) unsigned short sA[2][128 * 32];
    __shared__ __align__(16) unsigned short sB[2][128 * 32];

    int b  = blockIdx.z;
    int m0 = blockIdx.y * 128;
    int n0 = blockIdx.x * 128;
    int tid = threadIdx.x;
    int lane = tid & 63;
    int wid = tid >> 6;
    int wm = wid >> 1, wn = wid & 1;

    int sr = tid >> 2;          // staging row 0..63 (and +64)
    int scb = tid & 3;          // staging 16B block
    int swA0 = swz(sr, scb), swA1 = swz(sr + 64, scb);

    const unsigned short* Wt = Wb + (size_t)m0 * K + scb * 8;
    const unsigned short* Xt = X + ((size_t)b * NL + n0) * K + scb * 8;

    f32x4 acc[4][4] = {};

    // prologue: tile 0
    bfrag a0 = *(const bfrag*)&Wt[(size_t)sr * K];
    bfrag a1 = *(const bfrag*)&Wt[(size_t)(sr + 64) * K];
    bfrag b0 = *(const bfrag*)&Xt[(size_t)sr * K];
    bfrag b1 = *(const bfrag*)&Xt[(size_t)(sr + 64) * K];
    *(bfrag*)&sA[0][swA0] = a0;
    *(bfrag*)&sA[0][swA1] = a1;
    *(bfrag*)&sB[0][swA0] = b0;
    *(bfrag*)&sB[0][swA1] = b1;
    __syncthreads();

    const int nkt = K / 32;
    int cur = 0;
#pragma unroll 2
    for (int t = 0; t < nkt; t++) {
        bfrag na0, na1, nb0, nb1;
        bool more = (t + 1 < nkt);
        if (more) {
            int kk = (t + 1) * 32;
            na0 = *(const bfrag*)&Wt[(size_t)sr * K + kk];
            na1 = *(const bfrag*)&Wt[(size_t)(sr + 64) * K + kk];
            nb0 = *(const bfrag*)&Xt[(size_t)sr * K + kk];
            nb1 = *(const bfrag*)&Xt[(size_t)(sr + 64) * K + kk];
        }
        bfrag af[4], bf[4];
#pragma unroll
        for (int mi = 0; mi < 4; mi++) {
            int r = wm * 64 + mi * 16 + (lane & 15);
            af[mi] = *(const bfrag*)&sA[cur][swz(r, lane >> 4)];
        }
#pragma unroll
        for (int ni = 0; ni < 4; ni++) {
            int r = wn * 64 + ni * 16 + (lane & 15);
            bf[ni] = *(const bfrag*)&sB[cur][swz(r, lane >> 4)];
        }
#pragma unroll
        for (int mi = 0; mi < 4; mi++)
#pragma unroll
            for (int ni = 0; ni < 4; ni++)
                acc[mi][ni] = __builtin_amdgcn_mfma_f32_16x16x32_bf16(
                    af[mi], bf[ni], acc[mi][ni], 0, 0, 0);
        if (more) {
            *(bfrag*)&sA[cur ^ 1][swA0] = na0;
            *(bfrag*)&sA[cur ^ 1][swA1] = na1;
            *(bfrag*)&sB[cur ^ 1][swA0] = nb0;
            *(bfrag*)&sB[cur ^ 1][swA1] = nb1;
            __syncthreads();
            cur ^= 1;
        }
    }

    // epilogue: C frag -> col = lane&15 (n), row = (lane>>4)*4 + j (m)
    int col = lane & 15, rg = (lane >> 4) << 2;
#pragma unroll
    for (int mi = 0; mi < 4; mi++) {
        int m = m0 + wm * 64 + mi * 16 + rg;
        f32x4 bv = *(const f32x4*)&bias[m];
#pragma unroll
        for (int ni = 0; ni < 4; ni++) {
            int n = n0 + wn * 64 + ni * 16 + col;
            f32x4 c = acc[mi][ni];
            if (LAYER == 0) {
                unsigned short* dst = (unsigned short*)outp + ((size_t)b * NL + n) * CO + m;
                ushort4b o;
                o[0] = f2bf(c[0] + bv[0]); o[1] = f2bf(c[1] + bv[1]);
                o[2] = f2bf(c[2] + bv[2]); o[3] = f2bf(c[3] + bv[3]);
                *(ushort4b*)dst = o;
            } else {
                float* dst = (float*)outp;
#pragma unroll
                for (int j = 0; j < 4; j++)
                    dst[((size_t)b * CO + m + j) * NL + n] = c[j] + bv[j];
            }
        }
    }
}

// ---------------------------------------------------------------------------
// stats over n-major bf16 y0 (65536 rows x 256 ch) -> atomic partial sums
// ---------------------------------------------------------------------------
__global__ __launch_bounds__(256) void k_stats0(const unsigned short* __restrict__ y,
                                                float* __restrict__ psum,
                                                float* __restrict__ psq) {
    int r0 = blockIdx.x * 256;
    int lane = threadIdx.x & 63, wid = threadIdx.x >> 6;
    float s[4] = {0, 0, 0, 0}, q[4] = {0, 0, 0, 0};
    for (int j = 0; j < 64; j++) {
        int r = r0 + wid * 64 + j;
        ushort4b v = *(const ushort4b*)&y[(size_t)r * CO + lane * 4];
#pragma unroll
        for (int e = 0; e < 4; e++) {
            float f = bf2f(v[e]);
            s[e] += f; q[e] += f * f;
        }
    }
    __shared__ float ls[4][256], lq[4][256];
#pragma unroll
    for (int e = 0; e < 4; e++) {
        ls[wid][lane * 4 + e] = s[e];
        lq[wid][lane * 4 + e] = q[e];
    }
    __syncthreads();
    int c = threadIdx.x;
    float S = ls[0][c] + ls[1][c] + ls[2][c] + ls[3][c];
    float Q = lq[0][c] + lq[1][c] + lq[2][c] + lq[3][c];
    atomicAdd(&psum[c], S);
    atomicAdd(&psq[c], Q);
}

__global__ void k_fin(const float* __restrict__ psum, const float* __restrict__ psq,
                      const float* __restrict__ gamma, const float* __restrict__ beta,
                      float* __restrict__ scale, float* __restrict__ shift) {
    int c = threadIdx.x;
    float N = (float)(BB * NL);
    float mean = psum[c] / N;
    float var = psq[c] / N - mean * mean;
    float sc = gamma[c] / sqrtf(var + BN_EPS);
    scale[c] = sc;
    shift[c] = beta[c] - mean * sc;
}

// ---------------------------------------------------------------------------
// BN0 + ReLU in place on n-major bf16 y0
// ---------------------------------------------------------------------------
__global__ __launch_bounds__(256) void k_bn0(unsigned short* __restrict__ y,
                                             const float* __restrict__ scale,
                                             const float* __restrict__ shift) {
    size_t i = (size_t)blockIdx.x * 256 + threadIdx.x;      // short8 index
    unsigned short* p = y + i * 8;
    int cb = (int)(i & 31) * 8;
    bfrag v = *(bfrag*)p;
    f32x4 s0 = *(const f32x4*)&scale[cb], s1 = *(const f32x4*)&scale[cb + 4];
    f32x4 h0 = *(const f32x4*)&shift[cb], h1 = *(const f32x4*)&shift[cb + 4];
    bfrag o;
#pragma unroll
    for (int e = 0; e < 4; e++)
        o[e] = (short)f2bf(fmaxf(fmaf(s0[e], bf2f((unsigned short)v[e]), h0[e]), 0.f));
#pragma unroll
    for (int e = 0; e < 4; e++)
        o[4 + e] = (short)f2bf(fmaxf(fmaf(s1[e], bf2f((unsigned short)v[4 + e]), h1[e]), 0.f));
    *(bfrag*)p = o;
}

// ---------------------------------------------------------------------------
// stats over f32 o-major out (block = channel), writes scale/shift directly
// ---------------------------------------------------------------------------
__global__ __launch_bounds__(256) void k_stats1(const float* __restrict__ y,
                                                const float* __restrict__ gamma,
                                                const float* __restrict__ beta,
                                                float* __restrict__ scale,
                                                float* __restrict__ shift) {
    int o = blockIdx.x;
    float s = 0.f, q = 0.f;
    for (int b = 0; b < BB; b++) {
        const float4* row = (const float4*)(y + ((size_t)b * CO + o) * NL);
        for (int i = threadIdx.x; i < NL / 4; i += 256) {
            float4 v = row[i];
            s += v.x + v.y + v.z + v.w;
            q += v.x * v.x + v.y * v.y + v.z * v.z + v.w * v.w;
        }
    }
    __shared__ float ls[256], lq[256];
    ls[threadIdx.x] = s; lq[threadIdx.x] = q;
    __syncthreads();
    for (int st = 128; st > 0; st >>= 1) {
        if (threadIdx.x < st) {
            ls[threadIdx.x] += ls[threadIdx.x + st];
            lq[threadIdx.x] += lq[threadIdx.x + st];
        }
        __syncthreads();
    }
    if (threadIdx.x == 0) {
        float N = (float)(BB * NL);
        float mean = ls[0] / N;
        float var = lq[0] / N - mean * mean;
        float sc = gamma[o] / sqrtf(var + BN_EPS);
        scale[o] = sc;
        shift[o] = beta[o] - mean * sc;
    }
}

// ---------------------------------------------------------------------------
// final BN1 + ReLU in place on f32 out
// ---------------------------------------------------------------------------
__global__ __launch_bounds__(256) void k_bnrelu(float* __restrict__ y,
                                                const float* __restrict__ scale,
                                                const float* __restrict__ shift) {
    size_t i = (size_t)blockIdx.x * 256 + threadIdx.x;
    float4 v = ((float4*)y)[i];
    size_t e0 = i * 4;
    int c = (int)((e0 / NL) % CO);
    float sc = scale[c], sh = shift[c];
    v.x = fmaxf(fmaf(sc, v.x, sh), 0.f);
    v.y = fmaxf(fmaf(sc, v.y, sh), 0.f);
    v.z = fmaxf(fmaf(sc, v.z, sh), 0.f);
    v.w = fmaxf(fmaf(sc, v.w, sh), 0.f);
    ((float4*)y)[i] = v;
}

// ---------------------------------------------------------------------------
extern "C" void kernel_launch(void* const* d_in, const int* in_sizes, int n_in,
                              void* d_out, int out_size, void* d_ws, size_t ws_size,
                              hipStream_t stream) {
    const float* xyz_low   = (const float*)d_in[0];
    const float* xyz_high  = (const float*)d_in[1];
    const float* feat_low  = (const float*)d_in[2];
    const float* feat_high = (const float*)d_in[3];
    const float* W0  = (const float*)d_in[4];
    const float* b0  = (const float*)d_in[5];
    const float* g0  = (const float*)d_in[6];
    const float* be0 = (const float*)d_in[7];
    const float* W1  = (const float*)d_in[8];
    const float* b1  = (const float*)d_in[9];
    const float* g1  = (const float*)d_in[10];
    const float* be1 = (const float*)d_in[11];
    float* out = (float*)d_out;

    char* ws = (char*)d_ws;
    unsigned short* Xb  = (unsigned short*)ws;                         // 48 MB
    unsigned short* y0  = (unsigned short*)(ws + ((size_t)48 << 20));  // 32 MB
    float* fT           = (float*)(ws + ((size_t)80 << 20));           // 16 MB
    int*   idx          = (int*)  (ws + ((size_t)96 << 20));           // 768 KB
    float* wgt          = (float*)(ws + ((size_t)96 << 20) + 786432);  // 768 KB
    unsigned short* Wb0 = (unsigned short*)(ws + ((size_t)96 << 20) + 2 * 786432);
    unsigned short* Wb1 = Wb0 + CO * K0;
    float* psum         = (float*)(Wb1 + CO * K1);
    float* psq          = psum + 256;
    float* scale0       = psq + 256;
    float* shift0       = scale0 + 256;
    float* scale1       = shift0 + 256;
    float* shift1       = scale1 + 256;

    k_cvt<<<(CO * K0 + 255) / 256, 256, 0, stream>>>(W0, Wb0, CO * K0);
    k_cvt<<<(CO * K1 + 255) / 256, 256, 0, stream>>>(W1, Wb1, CO * K1);
    k_transpose_fh<<<dim3(NH / 32, CHH / 32, BB), 256, 0, stream>>>(feat_high, fT);
    k_knn<<<dim3(NL / 256, BB), 256, 0, stream>>>(xyz_low, xyz_high, idx, wgt);
    k_interp<<<dim3(NL / 16, BB), 256, 0, stream>>>(fT, idx, wgt, Xb);
    k_fl_t<<<dim3(NL / 64, CL / 32, BB), 256, 0, stream>>>(feat_low, Xb);
    hipMemsetAsync(psum, 0, 2 * 256 * sizeof(float), stream);

    k_gemm<0><<<dim3(NL / 128, CO / 128, BB), 256, 0, stream>>>(Xb, Wb0, b0, y0);
    k_stats0<<<256, 256, 0, stream>>>(y0, psum, psq);
    k_fin<<<1, 256, 0, stream>>>(psum, psq, g0, be0, scale0, shift0);
    k_bn0<<<(BB * NL * CO / 8) / 256, 256, 0, stream>>>(y0, scale0, shift0);
    k_gemm<1><<<dim3(NL / 128, CO / 128, BB), 256, 0, stream>>>(y0, Wb1, b1, out);
    k_stats1<<<CO, 256, 0, stream>>>(out, g1, be1, scale1, shift1);
    k_bnrelu<<<(BB * CO * NL / 4) / 256, 256, 0, stream>>>(out, scale1, shift1);
}

// Round 3
// 205.304 us; speedup vs baseline: 3.1079x; 1.5774x over previous
//
#include <hip/hip_runtime.h>
#include <math.h>

#define BB 16
#define NL 4096
#define NH 1024
#define CL 128
#define CHH 256
#define K0 384
#define K1 256
#define CO 256
#define BN_EPS 1e-5f

typedef __attribute__((ext_vector_type(8))) short bfrag;     // 8 bf16
typedef __attribute__((ext_vector_type(4))) float f32x4;
typedef __attribute__((ext_vector_type(4))) unsigned short ushort4b;

__device__ inline unsigned short f2bf(float f) {
    unsigned int u = __builtin_bit_cast(unsigned int, f);
    u += 0x7fffu + ((u >> 16) & 1u);                 // RNE
    return (unsigned short)(u >> 16);
}
__device__ inline float bf2f(unsigned short h) {
    unsigned int u = ((unsigned int)h) << 16;
    return __builtin_bit_cast(float, u);
}

// ---------------------------------------------------------------------------
// transpose feat_high (B, CH, NH) -> fT (B, NH, CH)   (f32, for the gather)
// ---------------------------------------------------------------------------
__global__ __launch_bounds__(256) void k_transpose_fh(const float* __restrict__ fh,
                                                      float* __restrict__ fT) {
    __shared__ float s[32][33];
    int b = blockIdx.z;
    int c0 = blockIdx.y * 32;
    int m0 = blockIdx.x * 32;
    int tx = threadIdx.x % 32, ty = threadIdx.x / 32;
    const float* src = fh + (size_t)b * CHH * NH;
    float* dst = fT + (size_t)b * NH * CHH;
#pragma unroll
    for (int j = 0; j < 4; j++)
        s[ty + 8 * j][tx] = src[(size_t)(c0 + ty + 8 * j) * NH + m0 + tx];
    __syncthreads();
#pragma unroll
    for (int j = 0; j < 4; j++)
        dst[(size_t)(m0 + ty + 8 * j) * CHH + c0 + tx] = s[tx][ty + 8 * j];
}

// ---------------------------------------------------------------------------
// 3-NN search, v2: 4 threads per low point (256 candidates each), branchless
// top-3 on clamped d^2 (monotone w/ ref's d ordering; exact __f*_rn op order),
// stable merge across segments, sqrt only for the 3 winners.
// Block: 256 threads = 64 points x 4 segments. Grid: (NL/64, B).
// ---------------------------------------------------------------------------
__global__ __launch_bounds__(256) void k_knn(const float* __restrict__ xyzl,
                                             const float* __restrict__ xyzh,
                                             int* __restrict__ idx,
                                             float* __restrict__ wgt) {
    __shared__ float4 cand[NH];          // x, y, z, sum(x^2)
    __shared__ float tls[64][4][3];
    __shared__ int   ils[64][4][3];

    int b = blockIdx.y;
    const float* xh = xyzh + (size_t)b * NH * 3;
    for (int p = threadIdx.x; p < NH; p += 256) {
        float x = xh[3 * p], y = xh[3 * p + 1], z = xh[3 * p + 2];
        float ss = __fadd_rn(__fadd_rn(__fmul_rn(x, x), __fmul_rn(y, y)),
                             __fmul_rn(z, z));
        cand[p] = make_float4(x, y, z, ss);
    }
    __syncthreads();

    int pp = threadIdx.x >> 2;           // point within block
    int s  = threadIdx.x & 3;            // candidate segment
    int n  = blockIdx.x * 64 + pp;
    const float* xl = xyzl + ((size_t)b * NL + n) * 3;
    float l0 = xl[0], l1 = xl[1], l2 = xl[2];
    float a = __fadd_rn(__fadd_rn(__fmul_rn(l0, l0), __fmul_rn(l1, l1)),
                        __fmul_rn(l2, l2));

    float t0 = INFINITY, t1 = INFINITY, t2 = INFINITY;
    int i0 = 0, i1 = 0, i2 = 0;
    int mbase = s * 256;
#pragma unroll 4
    for (int j = 0; j < 256; j++) {
        float4 c = cand[mbase + j];
        float dot = __fadd_rn(__fadd_rn(__fmul_rn(l0, c.x), __fmul_rn(l1, c.y)),
                              __fmul_rn(l2, c.z));
        float dd = __fsub_rn(__fadd_rn(a, c.w), __fmul_rn(2.0f, dot));
        dd = fmaxf(dd, 0.0f);
        int m = mbase + j;
        bool c0 = dd < t0, c1 = dd < t1, c2 = dd < t2;
        t2 = c1 ? t1 : (c2 ? dd : t2);
        i2 = c1 ? i1 : (c2 ? m : i2);
        t1 = c0 ? t0 : (c1 ? dd : t1);
        i1 = c0 ? i0 : (c1 ? m : i1);
        t0 = c0 ? dd : t0;
        i0 = c0 ? m : i0;
    }
    tls[pp][s][0] = t0; tls[pp][s][1] = t1; tls[pp][s][2] = t2;
    ils[pp][s][0] = i0; ils[pp][s][1] = i1; ils[pp][s][2] = i2;
    __syncthreads();

    if (threadIdx.x < 64) {
        int p = threadIdx.x;
        float u0 = tls[p][0][0], u1 = tls[p][0][1], u2 = tls[p][0][2];
        int   j0 = ils[p][0][0], j1 = ils[p][0][1], j2 = ils[p][0][2];
#pragma unroll
        for (int sg = 1; sg < 4; sg++) {
#pragma unroll
            for (int e = 0; e < 3; e++) {
                float dd = tls[p][sg][e];
                int m = ils[p][sg][e];
                bool c0 = dd < u0, c1 = dd < u1, c2 = dd < u2;
                u2 = c1 ? u1 : (c2 ? dd : u2);
                j2 = c1 ? j1 : (c2 ? m : j2);
                u1 = c0 ? u0 : (c1 ? dd : u1);
                j1 = c0 ? j0 : (c1 ? m : j1);
                u0 = c0 ? dd : u0;
                j0 = c0 ? m : j0;
            }
        }
        float d0 = sqrtf(u0), d1 = sqrtf(u1), d2 = sqrtf(u2);
        float w0 = 1.0f / fmaxf(d0, 1e-8f);
        float w1 = 1.0f / fmaxf(d1, 1e-8f);
        float w2 = 1.0f / fmaxf(d2, 1e-8f);
        float wsum = __fadd_rn(__fadd_rn(w0, w1), w2);
        w0 /= wsum; w1 /= wsum; w2 /= wsum;
        int nn = blockIdx.x * 64 + p;
        size_t base = ((size_t)b * NL + nn) * 3;
        idx[base] = j0; idx[base + 1] = j1; idx[base + 2] = j2;
        wgt[base] = w0; wgt[base + 1] = w1; wgt[base + 2] = w2;
    }
}

// ---------------------------------------------------------------------------
// interpolate -> Xb[b][n][c] bf16, c in [0, 256)
// ---------------------------------------------------------------------------
__global__ __launch_bounds__(256) void k_interp(const float* __restrict__ fT,
                                                const int* __restrict__ idx,
                                                const float* __restrict__ wgt,
                                                unsigned short* __restrict__ Xb) {
    int b = blockIdx.y;
    int n0 = blockIdx.x * 16;
    int c = threadIdx.x;
    const float* fTb = fT + (size_t)b * NH * CHH;
    for (int j = 0; j < 16; j++) {
        size_t base = ((size_t)b * NL + n0 + j) * 3;
        int m0 = idx[base], m1 = idx[base + 1], m2 = idx[base + 2];
        float w0 = wgt[base], w1 = wgt[base + 1], w2 = wgt[base + 2];
        float f = __fadd_rn(__fadd_rn(__fmul_rn(w0, fTb[(size_t)m0 * CHH + c]),
                                      __fmul_rn(w1, fTb[(size_t)m1 * CHH + c])),
                            __fmul_rn(w2, fTb[(size_t)m2 * CHH + c]));
        Xb[((size_t)b * NL + n0 + j) * K0 + c] = f2bf(f);
    }
}

// ---------------------------------------------------------------------------
// feat_low (B, CL, NL) f32 -> Xb[b][n][256 + c] bf16   (transpose-convert)
// ---------------------------------------------------------------------------
__global__ __launch_bounds__(256) void k_fl_t(const float* __restrict__ fl,
                                              unsigned short* __restrict__ Xb) {
    __shared__ unsigned short s[32][68];
    int b = blockIdx.z, c0 = blockIdx.y * 32, n0 = blockIdx.x * 64;
    int tx = threadIdx.x & 63, ty = threadIdx.x >> 6;       // 64 x 4
    const float* src = fl + ((size_t)b * CL + c0) * NL + n0;
#pragma unroll
    for (int i = 0; i < 8; i++) {
        int c = ty * 8 + i;
        s[c][tx] = f2bf(src[(size_t)c * NL + tx]);
    }
    __syncthreads();
    int n = threadIdx.x >> 2, q = threadIdx.x & 3;
    ushort4b o0, o1;
#pragma unroll
    for (int e = 0; e < 4; e++) o0[e] = s[q * 8 + e][n];
#pragma unroll
    for (int e = 0; e < 4; e++) o1[e] = s[q * 8 + 4 + e][n];
    unsigned short* dst = Xb + ((size_t)b * NL + n0 + n) * K0 + CHH + c0 + q * 8;
    *(ushort4b*)dst = o0;
    *(ushort4b*)(dst + 4) = o1;
}

// ---------------------------------------------------------------------------
// f32 -> bf16 convert (weights)
// ---------------------------------------------------------------------------
__global__ __launch_bounds__(256) void k_cvt(const float* __restrict__ src,
                                             unsigned short* __restrict__ dst, int n) {
    int i = blockIdx.x * 256 + threadIdx.x;
    if (i < n) dst[i] = f2bf(src[i]);
}

// ---------------------------------------------------------------------------
// MFMA GEMM: C[m][n] = sum_k W[m][k] * X[n][k],  X n-major bf16.
// 128x128 tile, BK=32, 4 waves (64x64 each), XOR-swizzled LDS, double buffer.
// LAYER 0: out = y0[b][n][m] bf16 (+bias).  LAYER 1: out = f32 [b][m][n] (+bias).
// ---------------------------------------------------------------------------
__device__ inline int swz(int r, int cb) {
    return r * 32 + ((cb ^ ((r >> 1) & 3)) << 3);   // short index, 16B blocks
}

template <int LAYER>
__global__ __launch_bounds__(256) void k_gemm(const unsigned short* __restrict__ X,
                                              const unsigned short* __restrict__ Wb,
                                              const float* __restrict__ bias,
                                              void* __restrict__ outp) {
    const int K = (LAYER == 0) ? K0 : K1;
    __shared__ __align__(16) unsigned short sA[2][128 * 32];
    __shared__ __align__(16) unsigned short sB[2][128 * 32];

    int b  = blockIdx.z;
    int m0 = blockIdx.y * 128;
    int n0 = blockIdx.x * 128;
    int tid = threadIdx.x;
    int lane = tid & 63;
    int wid = tid >> 6;
    int wm = wid >> 1, wn = wid & 1;

    int sr = tid >> 2;          // staging row 0..63 (and +64)
    int scb = tid & 3;          // staging 16B block
    int swA0 = swz(sr, scb), swA1 = swz(sr + 64, scb);

    const unsigned short* Wt = Wb + (size_t)m0 * K + scb * 8;
    const unsigned short* Xt = X + ((size_t)b * NL + n0) * K + scb * 8;

    f32x4 acc[4][4] = {};

    // prologue: tile 0
    bfrag a0 = *(const bfrag*)&Wt[(size_t)sr * K];
    bfrag a1 = *(const bfrag*)&Wt[(size_t)(sr + 64) * K];
    bfrag b0 = *(const bfrag*)&Xt[(size_t)sr * K];
    bfrag b1 = *(const bfrag*)&Xt[(size_t)(sr + 64) * K];
    *(bfrag*)&sA[0][swA0] = a0;
    *(bfrag*)&sA[0][swA1] = a1;
    *(bfrag*)&sB[0][swA0] = b0;
    *(bfrag*)&sB[0][swA1] = b1;
    __syncthreads();

    const int nkt = K / 32;
    int cur = 0;
#pragma unroll 2
    for (int t = 0; t < nkt; t++) {
        bfrag na0, na1, nb0, nb1;
        bool more = (t + 1 < nkt);
        if (more) {
            int kk = (t + 1) * 32;
            na0 = *(const bfrag*)&Wt[(size_t)sr * K + kk];
            na1 = *(const bfrag*)&Wt[(size_t)(sr + 64) * K + kk];
            nb0 = *(const bfrag*)&Xt[(size_t)sr * K + kk];
            nb1 = *(const bfrag*)&Xt[(size_t)(sr + 64) * K + kk];
        }
        bfrag af[4], bf[4];
#pragma unroll
        for (int mi = 0; mi < 4; mi++) {
            int r = wm * 64 + mi * 16 + (lane & 15);
            af[mi] = *(const bfrag*)&sA[cur][swz(r, lane >> 4)];
        }
#pragma unroll
        for (int ni = 0; ni < 4; ni++) {
            int r = wn * 64 + ni * 16 + (lane & 15);
            bf[ni] = *(const bfrag*)&sB[cur][swz(r, lane >> 4)];
        }
#pragma unroll
        for (int mi = 0; mi < 4; mi++)
#pragma unroll
            for (int ni = 0; ni < 4; ni++)
                acc[mi][ni] = __builtin_amdgcn_mfma_f32_16x16x32_bf16(
                    af[mi], bf[ni], acc[mi][ni], 0, 0, 0);
        if (more) {
            *(bfrag*)&sA[cur ^ 1][swA0] = na0;
            *(bfrag*)&sA[cur ^ 1][swA1] = na1;
            *(bfrag*)&sB[cur ^ 1][swA0] = nb0;
            *(bfrag*)&sB[cur ^ 1][swA1] = nb1;
            __syncthreads();
            cur ^= 1;
        }
    }

    // epilogue: C frag -> col = lane&15 (n), row = (lane>>4)*4 + j (m)
    int col = lane & 15, rg = (lane >> 4) << 2;
#pragma unroll
    for (int mi = 0; mi < 4; mi++) {
        int m = m0 + wm * 64 + mi * 16 + rg;
        f32x4 bv = *(const f32x4*)&bias[m];
#pragma unroll
        for (int ni = 0; ni < 4; ni++) {
            int n = n0 + wn * 64 + ni * 16 + col;
            f32x4 c = acc[mi][ni];
            if (LAYER == 0) {
                unsigned short* dst = (unsigned short*)outp + ((size_t)b * NL + n) * CO + m;
                ushort4b o;
                o[0] = f2bf(c[0] + bv[0]); o[1] = f2bf(c[1] + bv[1]);
                o[2] = f2bf(c[2] + bv[2]); o[3] = f2bf(c[3] + bv[3]);
                *(ushort4b*)dst = o;
            } else {
                float* dst = (float*)outp;
#pragma unroll
                for (int j = 0; j < 4; j++)
                    dst[((size_t)b * CO + m + j) * NL + n] = c[j] + bv[j];
            }
        }
    }
}

// ---------------------------------------------------------------------------
// stats over n-major bf16 y0 (65536 rows x 256 ch) -> atomic partial sums
// ---------------------------------------------------------------------------
__global__ __launch_bounds__(256) void k_stats0(const unsigned short* __restrict__ y,
                                                float* __restrict__ psum,
                                                float* __restrict__ psq) {
    int r0 = blockIdx.x * 256;
    int lane = threadIdx.x & 63, wid = threadIdx.x >> 6;
    float s[4] = {0, 0, 0, 0}, q[4] = {0, 0, 0, 0};
    for (int j = 0; j < 64; j++) {
        int r = r0 + wid * 64 + j;
        ushort4b v = *(const ushort4b*)&y[(size_t)r * CO + lane * 4];
#pragma unroll
        for (int e = 0; e < 4; e++) {
            float f = bf2f(v[e]);
            s[e] += f; q[e] += f * f;
        }
    }
    __shared__ float ls[4][256], lq[4][256];
#pragma unroll
    for (int e = 0; e < 4; e++) {
        ls[wid][lane * 4 + e] = s[e];
        lq[wid][lane * 4 + e] = q[e];
    }
    __syncthreads();
    int c = threadIdx.x;
    float S = ls[0][c] + ls[1][c] + ls[2][c] + ls[3][c];
    float Q = lq[0][c] + lq[1][c] + lq[2][c] + lq[3][c];
    atomicAdd(&psum[c], S);
    atomicAdd(&psq[c], Q);
}

__global__ void k_fin(const float* __restrict__ psum, const float* __restrict__ psq,
                      const float* __restrict__ gamma, const float* __restrict__ beta,
                      float* __restrict__ scale, float* __restrict__ shift) {
    int c = threadIdx.x;
    float N = (float)(BB * NL);
    float mean = psum[c] / N;
    float var = psq[c] / N - mean * mean;
    float sc = gamma[c] / sqrtf(var + BN_EPS);
    scale[c] = sc;
    shift[c] = beta[c] - mean * sc;
}

// ---------------------------------------------------------------------------
// BN0 + ReLU in place on n-major bf16 y0
// ---------------------------------------------------------------------------
__global__ __launch_bounds__(256) void k_bn0(unsigned short* __restrict__ y,
                                             const float* __restrict__ scale,
                                             const float* __restrict__ shift) {
    size_t i = (size_t)blockIdx.x * 256 + threadIdx.x;      // short8 index
    unsigned short* p = y + i * 8;
    int cb = (int)(i & 31) * 8;
    bfrag v = *(bfrag*)p;
    f32x4 s0 = *(const f32x4*)&scale[cb], s1 = *(const f32x4*)&scale[cb + 4];
    f32x4 h0 = *(const f32x4*)&shift[cb], h1 = *(const f32x4*)&shift[cb + 4];
    bfrag o;
#pragma unroll
    for (int e = 0; e < 4; e++)
        o[e] = (short)f2bf(fmaxf(fmaf(s0[e], bf2f((unsigned short)v[e]), h0[e]), 0.f));
#pragma unroll
    for (int e = 0; e < 4; e++)
        o[4 + e] = (short)f2bf(fmaxf(fmaf(s1[e], bf2f((unsigned short)v[4 + e]), h1[e]), 0.f));
    *(bfrag*)p = o;
}

// ---------------------------------------------------------------------------
// stats over f32 o-major out (block = channel), writes scale/shift directly
// ---------------------------------------------------------------------------
__global__ __launch_bounds__(256) void k_stats1(const float* __restrict__ y,
                                                const float* __restrict__ gamma,
                                                const float* __restrict__ beta,
                                                float* __restrict__ scale,
                                                float* __restrict__ shift) {
    int o = blockIdx.x;
    float s = 0.f, q = 0.f;
    for (int b = 0; b < BB; b++) {
        const float4* row = (const float4*)(y + ((size_t)b * CO + o) * NL);
        for (int i = threadIdx.x; i < NL / 4; i += 256) {
            float4 v = row[i];
            s += v.x + v.y + v.z + v.w;
            q += v.x * v.x + v.y * v.y + v.z * v.z + v.w * v.w;
        }
    }
    __shared__ float ls[256], lq[256];
    ls[threadIdx.x] = s; lq[threadIdx.x] = q;
    __syncthreads();
    for (int st = 128; st > 0; st >>= 1) {
        if (threadIdx.x < st) {
            ls[threadIdx.x] += ls[threadIdx.x + st];
            lq[threadIdx.x] += lq[threadIdx.x + st];
        }
        __syncthreads();
    }
    if (threadIdx.x == 0) {
        float N = (float)(BB * NL);
        float mean = ls[0] / N;
        float var = lq[0] / N - mean * mean;
        float sc = gamma[o] / sqrtf(var + BN_EPS);
        scale[o] = sc;
        shift[o] = beta[o] - mean * sc;
    }
}

// ---------------------------------------------------------------------------
// final BN1 + ReLU in place on f32 out
// ---------------------------------------------------------------------------
__global__ __launch_bounds__(256) void k_bnrelu(float* __restrict__ y,
                                                const float* __restrict__ scale,
                                                const float* __restrict__ shift) {
    size_t i = (size_t)blockIdx.x * 256 + threadIdx.x;
    float4 v = ((float4*)y)[i];
    size_t e0 = i * 4;
    int c = (int)((e0 / NL) % CO);
    float sc = scale[c], sh = shift[c];
    v.x = fmaxf(fmaf(sc, v.x, sh), 0.f);
    v.y = fmaxf(fmaf(sc, v.y, sh), 0.f);
    v.z = fmaxf(fmaf(sc, v.z, sh), 0.f);
    v.w = fmaxf(fmaf(sc, v.w, sh), 0.f);
    ((float4*)y)[i] = v;
}

// ---------------------------------------------------------------------------
extern "C" void kernel_launch(void* const* d_in, const int* in_sizes, int n_in,
                              void* d_out, int out_size, void* d_ws, size_t ws_size,
                              hipStream_t stream) {
    const float* xyz_low   = (const float*)d_in[0];
    const float* xyz_high  = (const float*)d_in[1];
    const float* feat_low  = (const float*)d_in[2];
    const float* feat_high = (const float*)d_in[3];
    const float* W0  = (const float*)d_in[4];
    const float* b0  = (const float*)d_in[5];
    const float* g0  = (const float*)d_in[6];
    const float* be0 = (const float*)d_in[7];
    const float* W1  = (const float*)d_in[8];
    const float* b1  = (const float*)d_in[9];
    const float* g1  = (const float*)d_in[10];
    const float* be1 = (const float*)d_in[11];
    float* out = (float*)d_out;

    char* ws = (char*)d_ws;
    unsigned short* Xb  = (unsigned short*)ws;                         // 48 MB
    unsigned short* y0  = (unsigned short*)(ws + ((size_t)48 << 20));  // 32 MB
    float* fT           = (float*)(ws + ((size_t)80 << 20));           // 16 MB
    int*   idx          = (int*)  (ws + ((size_t)96 << 20));           // 768 KB
    float* wgt          = (float*)(ws + ((size_t)96 << 20) + 786432);  // 768 KB
    unsigned short* Wb0 = (unsigned short*)(ws + ((size_t)96 << 20) + 2 * 786432);
    unsigned short* Wb1 = Wb0 + CO * K0;
    float* psum         = (float*)(Wb1 + CO * K1);
    float* psq          = psum + 256;
    float* scale0       = psq + 256;
    float* shift0       = scale0 + 256;
    float* scale1       = shift0 + 256;
    float* shift1       = scale1 + 256;

    k_cvt<<<(CO * K0 + 255) / 256, 256, 0, stream>>>(W0, Wb0, CO * K0);
    k_cvt<<<(CO * K1 + 255) / 256, 256, 0, stream>>>(W1, Wb1, CO * K1);
    k_transpose_fh<<<dim3(NH / 32, CHH / 32, BB), 256, 0, stream>>>(feat_high, fT);
    k_knn<<<dim3(NL / 64, BB), 256, 0, stream>>>(xyz_low, xyz_high, idx, wgt);
    k_interp<<<dim3(NL / 16, BB), 256, 0, stream>>>(fT, idx, wgt, Xb);
    k_fl_t<<<dim3(NL / 64, CL / 32, BB), 256, 0, stream>>>(feat_low, Xb);
    hipMemsetAsync(psum, 0, 2 * 256 * sizeof(float), stream);

    k_gemm<0><<<dim3(NL / 128, CO / 128, BB), 256, 0, stream>>>(Xb, Wb0, b0, y0);
    k_stats0<<<256, 256, 0, stream>>>(y0, psum, psq);
    k_fin<<<1, 256, 0, stream>>>(psum, psq, g0, be0, scale0, shift0);
    k_bn0<<<(BB * NL * CO / 8) / 256, 256, 0, stream>>>(y0, scale0, shift0);
    k_gemm<1><<<dim3(NL / 128, CO / 128, BB), 256, 0, stream>>>(y0, Wb1, b1, out);
    k_stats1<<<CO, 256, 0, stream>>>(out, g1, be1, scale1, shift1);
    k_bnrelu<<<(BB * CO * NL / 4) / 256, 256, 0, stream>>>(out, scale1, shift1);
}